// Round 7
// baseline (221.809 us; speedup 1.0000x reference)
//
#include <hip/hip_runtime.h>
#include <stdint.h>

typedef __attribute__((ext_vector_type(8))) short bf16x8;
typedef __attribute__((ext_vector_type(4))) float f32x4;
typedef __attribute__((ext_vector_type(16))) float f32x16;
typedef __attribute__((ext_vector_type(2))) unsigned int uint2v;

// ---------------- workspace layout (bytes) ----------------
#define WS_WQKV   0u               // 384*256 bf16 = 196608
#define WS_WZ     196608u          // 256*128 bf16 = 65536
#define WS_SCL    262144u          // 384 f32 (QKV fused BN scale)
#define WS_SHF    263680u          // 384 f32 (QKV fused BN shift)
#define WS_WZS    265216u          // 256 f32 (out BN scale)
#define WS_WZT    266240u          // 256 f32 (out BN shift)
#define WS_Q      524288u          // [4][4096][128] bf16 row-major (pre-scaled by s2)
#define WS_K      (WS_Q  + 4194304u)   // [4][64 tile][16 grp][64 lane][8] bf16 frag-tiled (32x32)
#define WS_VT     (WS_K  + 4194304u)   // [4][64 tile][16 grp][64 lane][8] bf16 frag-tiled (32x32)
#define WS_Y      (WS_VT + 4194304u)   // (spare)
#define WS_OP     (WS_Y  + 4194304u)   // [4 mc][4 b][4096][128] bf16 partials = 16 MB
#define WS_LP     (WS_OP + 16777216u)  // [4 mc][4 b][4096] f32 partial denoms = 256 KB

__device__ __forceinline__ short f2bf(float f) {
  union { float f; uint32_t u; } v; v.f = f;
  uint32_t r = v.u + 0x7fffu + ((v.u >> 16) & 1u);
  return (short)(r >> 16);
}

// round-half-up pair pack: 2 floats -> 2 bf16 in one u32 (cheap, <=1ulp bias)
__device__ __forceinline__ uint32_t pack2_bf16(float a, float b) {
  union { float f; uint32_t u; } x, y; x.f = a; y.f = b;
  return ((y.u + 0x8000u) & 0xffff0000u) | ((x.u + 0x8000u) >> 16);
}

__device__ __forceinline__ f32x4 mfma16(bf16x8 a, bf16x8 b, f32x4 c) {
  return __builtin_amdgcn_mfma_f32_16x16x32_bf16(a, b, c, 0, 0, 0);
}
__device__ __forceinline__ f32x16 mfma32(bf16x8 a, bf16x8 b, f32x16 c) {
  return __builtin_amdgcn_mfma_f32_32x32x16_bf16(a, b, c, 0, 0, 0);
}

// async global->LDS DMA, 16B/lane: dest = wave-uniform base + lane*16
__device__ __forceinline__ void load_lds16(const short* gp, short* lp) {
  __builtin_amdgcn_global_load_lds(
      (const __attribute__((address_space(1))) uint32_t*)gp,
      (__attribute__((address_space(3))) uint32_t*)lp, 16, 0, 0);
}

// ---------------- kernel 0: weight prep + BN folding ----------------
__global__ __launch_bounds__(256) void prep_kernel(
    const float* theta_w, const float* phi_w, const float* g_w, const float* wz_w,
    const float* theta_b, const float* tg, const float* tb, const float* tm, const float* tv,
    const float* phi_b,   const float* pg, const float* pb, const float* pm, const float* pv,
    const float* g_b,
    const float* wz_b, const float* bg, const float* bb, const float* bm, const float* bv,
    char* ws) {
  int idx = blockIdx.x * 256 + threadIdx.x;
  short* wqkv = (short*)(ws + WS_WQKV);
  if (idx < 98304) {
    float w;
    if (idx < 32768) w = theta_w[idx];
    else if (idx < 65536) w = phi_w[idx - 32768];
    else w = g_w[idx - 65536];
    wqkv[idx] = f2bf(w);
  }
  if (idx < 32768) ((short*)(ws + WS_WZ))[idx] = f2bf(wz_w[idx]);
  if (idx < 384) {
    float s, t;
    if (idx < 128)      { s = tg[idx] * rsqrtf(tv[idx] + 1e-5f);
                          t = (theta_b[idx] - tm[idx]) * s + tb[idx]; }
    else if (idx < 256) { int d = idx - 128; s = pg[d] * rsqrtf(pv[d] + 1e-5f);
                          t = (phi_b[d] - pm[d]) * s + pb[d]; }
    else                { int d = idx - 256; s = 1.0f; t = g_b[d]; }
    ((float*)(ws + WS_SCL))[idx] = s;
    ((float*)(ws + WS_SHF))[idx] = t;
  }
  if (idx < 256) {
    float s = bg[idx] * rsqrtf(bv[idx] + 1e-5f);
    float t = (wz_b[idx] - bm[idx]) * s + bb[idx];
    ((float*)(ws + WS_WZS))[idx] = s;
    ((float*)(ws + WS_WZT))[idx] = t;
  }
}

// ---------------- kernel 1: fused Q/K/V projection (+BN fold) ----------------
// (unchanged from R14) Per-s operand swap: Q/K computed as mfma16(w,x) so each
// thread owns 4 consecutive d -> all stores are 8B short4. K/V written in the
// 32x32-MFMA fragment-tiled order consumed by attn:
//   K: tile=n>>6; grp=mb*8+ks (mb=(n&63)>>5, ks=c>>4); slot=h*32+(n&31),
//      h=(c>>3)&1; elem=c&7.
//   V: grp=dt*4+ks2 (dt=d>>5, ks2=(n&63)>>4); slot=hv*32+(d&31),
//      hv=((n&63)>>3)&1; elem=n&7.
__global__ __launch_bounds__(256) void qkv_kernel(const float* __restrict__ x, char* ws) {
  const int nt2 = blockIdx.x, b = blockIdx.y;
  const int t = threadIdx.x;
  __shared__ __attribute__((aligned(16))) short xs[16][264];
  const short* wqkv = (const short*)(ws + WS_WQKV);
  const float* scl = (const float*)(ws + WS_SCL);
  const float* shf = (const float*)(ws + WS_SHF);
  const int n0 = nt2 * 16;
  #pragma unroll
  for (int i = 0; i < 4; ++i) {
    int chunk = i * 256 + t;
    int c = chunk >> 2, n4 = chunk & 3;
    const float4 v = *(const float4*)(x + ((size_t)(b * 256 + c) << 12) + n0 + n4 * 4);
    xs[n4 * 4 + 0][c] = f2bf(v.x);
    xs[n4 * 4 + 1][c] = f2bf(v.y);
    xs[n4 * 4 + 2][c] = f2bf(v.z);
    xs[n4 * 4 + 3][c] = f2bf(v.w);
  }
  __syncthreads();
  const int wv = t >> 6, l = t & 63, lr = l & 15, q = l >> 4;
  bf16x8 a[8];
  #pragma unroll
  for (int kt = 0; kt < 8; ++kt) a[kt] = *(const bf16x8*)&xs[lr][kt * 32 + q * 8];
  f32x4 acc[6] = {};
  #pragma unroll
  for (int kt = 0; kt < 8; ++kt) {
    #pragma unroll
    for (int s = 0; s < 6; ++s) {
      const short* wp = wqkv + (size_t)(wv * 96 + s * 16 + lr) * 256 + kt * 32 + q * 8;
      bf16x8 bf = *(const bf16x8*)wp;
      // wave-uniform branch: Q/K swapped orientation, V original
      if (wv * 96 + s * 16 < 256) acc[s] = mfma16(bf, a[kt], acc[s]);
      else                        acc[s] = mfma16(a[kt], bf, acc[s]);
    }
  }
  const float s2 = 0.08838834764831845f * 1.4426950408889634f;
  short* Qp = (short*)(ws + WS_Q)  + ((size_t)b << 19);
  short* Kt = (short*)(ws + WS_K)  + ((size_t)b << 19);
  short* Vt = (short*)(ws + WS_VT) + ((size_t)b << 19);
  #pragma unroll
  for (int s = 0; s < 6; ++s) {
    int dgb = wv * 96 + s * 16;
    if (dgb < 256) {
      // swapped: thread owns d = dgb+q*4+r (4 consecutive), n = n0+lr
      const int n = n0 + lr;
      const int d4 = dgb + q * 4;
      short4 pk;
      {
        short vals[4];
        #pragma unroll
        for (int r = 0; r < 4; ++r) {
          int dg = d4 + r;
          float sc = scl[dg], sh = shf[dg];
          if (dgb < 128) { sc *= s2; sh *= s2; }   // fold softmax scale into Q
          vals[r] = f2bf(acc[s][r] * sc + sh);
        }
        pk.x = vals[0]; pk.y = vals[1]; pk.z = vals[2]; pk.w = vals[3];
      }
      if (dgb < 128) {
        *(short4*)(Qp + (size_t)n * 128 + d4) = pk;
      } else {
        int c4 = d4 - 128;
        int tile = n >> 6, nn = n & 63;
        int mb = nn >> 5, rr = nn & 31;
        int ks = c4 >> 4, h = (c4 >> 3) & 1, e0 = c4 & 7;   // e0 in {0,4}
        size_t base = (size_t)tile * 8192 + (size_t)(mb * 8 + ks) * 512
                    + (size_t)(h * 32 + rr) * 8 + e0;
        *(short4*)(Kt + base) = pk;
      }
    } else {
      // original orientation: V (thread owns 4 consecutive n at fixed d)
      int dg = dgb + lr;
      float sc = scl[dg], sh = shf[dg];
      short4 pk;
      pk.x = f2bf(acc[s][0] * sc + sh);
      pk.y = f2bf(acc[s][1] * sc + sh);
      pk.z = f2bf(acc[s][2] * sc + sh);
      pk.w = f2bf(acc[s][3] * sc + sh);
      int d = dg - 256;
      int nbase = n0 + q * 4;
      int tile = nbase >> 6, nn = nbase & 63;
      int dt = d >> 5, rv = d & 31;
      int ks2 = nn >> 4, hv = (nn >> 3) & 1, e0 = nn & 7;   // e0 in {0,4}
      size_t base = (size_t)tile * 8192 + (size_t)(dt * 4 + ks2) * 512
                  + (size_t)(hv * 32 + rv) * 8 + e0;
      *(short4*)(Vt + base) = pk;
    }
  }
}

// ---------------- kernel 2: flash attention, d-split occupancy x2 ------------
// R17: the R13 body is latency-bound: per CU ~8.2k cyc MFMA + ~12k VALU + ~49k
// LDS-unit vs 128k measured = ~31% issue-busy with 2 barrier-locked blocks/CU
// (R5: fewer waves worse; R2's occupancy-null was on the psl-LDS structure).
// This round doubles blocks/CU WITHOUT shrinking per-wave tiles: split PV's
// d-dimension. Each block computes the full S^T (duplicated, +16 mfma/tile --
// we are not MFMA-bound) but only half of O (d 0..63 or 64..127). Grid 512 ->
// 1024 (4b x 32nt x 4mc x 2dh); LDS single-buffered K 16KB + V-half 8KB = 24KB
// -> 4 blocks/CU = 16 waves/CU, barrier-desynced across 4 independent blocks.
// o[] halves -> ~76 VGPR, fits __launch_bounds__(256,4) cap of 128. OP stores
// are disjoint per d-half; LP written by dh=0 only (both halves compute it).
__global__ __launch_bounds__(256, 4) void attn_kernel(char* ws) {
  const int g = blockIdx.x;                      // 0..1023, XCD-swizzled
  const int b = (g & 7) >> 1;
  const int idx = ((g >> 3) << 1) | (g & 1);     // 0..255
  const int nt = idx >> 3;                       // 0..31
  const int mc = (idx >> 1) & 3;                 // 0..3
  const int dh = idx & 1;                        // 0..1  (d-half)
  const int t = threadIdx.x, w = t >> 6, l = t & 63;
  const int lq = l & 31, h = l >> 5;
  __shared__ __attribute__((aligned(16))) short ksl[16][512];   // grp mb*8+ks
  __shared__ __attribute__((aligned(16))) short vsl[8][512];    // grp dtl*4+ks2
  const short* Q  = (const short*)(ws + WS_Q)  + ((size_t)b << 19);
  const short* Kt = (const short*)(ws + WS_K)  + ((size_t)b << 19);
  const short* Vt = (const short*)(ws + WS_VT) + ((size_t)b << 19);
  const int n0w = nt * 128 + w * 32;
  // Q fragments resident as B-operands (pre-scaled by s2 in qkv):
  // col = lq = Q-row, k = ks*16 + h*8 + e
  bf16x8 qf[8];
  #pragma unroll
  for (int ks = 0; ks < 8; ++ks)
    qf[ks] = *(const bf16x8*)(Q + (size_t)(n0w + lq) * 128 + ks * 16 + h * 8);
  f32x16 o[2] = {};    // o[dtl]: O^T[32(dh*2+dtl) + row(reg,h)][q=lq]
  float lsum = 0.f;

  const short* kbase = Kt + (size_t)(mc * 16) * 8192;
  const short* vbase = Vt + (size_t)(mc * 16) * 8192 + (size_t)(dh * 8) * 512;

  for (int it = 0; it < 16; ++it) {
    __syncthreads();   // previous tile fully consumed
    {
      const short* kg = kbase + (size_t)it * 8192;
      const short* vg = vbase + (size_t)it * 8192;
      // 24 DMA groups: wave w stages K grps w*4..w*4+3 and V grps w*2..w*2+1
      #pragma unroll
      for (int i = 0; i < 4; ++i) {
        int gi = w * 4 + i;
        load_lds16(kg + gi * 512 + l * 8, &ksl[gi][0]);
      }
      #pragma unroll
      for (int i = 0; i < 2; ++i) {
        int gi = w * 2 + i;
        load_lds16(vg + gi * 512 + l * 8, &vsl[gi][0]);
      }
    }
    __syncthreads();   // vmcnt(0) drained here by compiler
    // S^T = K * Q^T : A = K-frag (row = kv, k = c), B = qf
    f32x16 sacc[2] = {};
    __builtin_amdgcn_s_setprio(1);
    #pragma unroll
    for (int ks = 0; ks < 8; ++ks) {
      #pragma unroll
      for (int mb = 0; mb < 2; ++mb) {
        bf16x8 kf = *(const bf16x8*)&ksl[mb * 8 + ks][l * 8];
        sacc[mb] = mfma32(kf, qf[ks], sacc[mb]);
      }
    }
    __builtin_amdgcn_s_setprio(0);
    // softmax + in-register P fragment build (T12): no LDS.
    bf16x8 pf[4];   // pf[2*mb+k] covers kv rows 32mb+16k .. +15
    #pragma unroll
    for (int mb = 0; mb < 2; ++mb) {
      float e[16];
      #pragma unroll
      for (int r = 0; r < 16; ++r) {
        e[r] = exp2f(sacc[mb][r]);
        lsum += e[r];
      }
      #pragma unroll
      for (int k = 0; k < 2; ++k) {
        uint32_t va0 = pack2_bf16(e[8 * k + 0], e[8 * k + 1]);
        uint32_t va1 = pack2_bf16(e[8 * k + 2], e[8 * k + 3]);
        uint32_t vb0 = pack2_bf16(e[8 * k + 4], e[8 * k + 5]);
        uint32_t vb1 = pack2_bf16(e[8 * k + 6], e[8 * k + 7]);
        uint2v s0 = __builtin_amdgcn_permlane32_swap(va0, vb0, false, false);
        uint2v s1 = __builtin_amdgcn_permlane32_swap(va1, vb1, false, false);
        union { uint32_t u[4]; bf16x8 v; } pk;
        pk.u[0] = s0[0]; pk.u[1] = s1[0]; pk.u[2] = s0[1]; pk.u[3] = s1[1];
        pf[2 * mb + k] = pk.v;
      }
    }
    // O^T += V^T * P^T : A = V-frag (row = d, k = kv), B = pf  (d-half only)
    __builtin_amdgcn_s_setprio(1);
    #pragma unroll
    for (int dtl = 0; dtl < 2; ++dtl) {
      #pragma unroll
      for (int ks2 = 0; ks2 < 4; ++ks2) {
        bf16x8 vf = *(const bf16x8*)&vsl[dtl * 4 + ks2][l * 8];
        o[dtl] = mfma32(vf, pf[ks2], o[dtl]);
      }
    }
    __builtin_amdgcn_s_setprio(0);
  }

  // epilogue: write unnormalized partials
  const int cb = mc * 4 + b;
  if (dh == 0) {
    float* LP = (float*)(ws + WS_LP) + ((size_t)cb << 12);
    float s = lsum;
    s += __shfl_xor(s, 32, 64);
    if (l < 32) LP[n0w + l] = s;
  }
  short* OPc = (short*)(ws + WS_OP) + ((size_t)cb << 19);
  #pragma unroll
  for (int dtl = 0; dtl < 2; ++dtl) {
    const int dt = dh * 2 + dtl;
    #pragma unroll
    for (int rg = 0; rg < 4; ++rg) {
      short4 pk;
      pk.x = f2bf(o[dtl][rg * 4 + 0]);
      pk.y = f2bf(o[dtl][rg * 4 + 1]);
      pk.z = f2bf(o[dtl][rg * 4 + 2]);
      pk.w = f2bf(o[dtl][rg * 4 + 3]);
      *(short4*)&OPc[((size_t)(n0w + lq) << 7) + dt * 32 + rg * 8 + h * 4] = pk;
    }
  }
}

// ---------------- kernel 3: merge partials + W_z projection + BN2d + residual ----
// grid (256 nt of 16 rows, 4 b); block 256 = 4 waves (wave = c-quarter).
__global__ __launch_bounds__(256) void proj_kernel(const float* __restrict__ x,
                                                   char* ws, float* __restrict__ out) {
  const int nt = blockIdx.x, b = blockIdx.y;
  const int t = threadIdx.x, wv = t >> 6, l = t & 63, lr = l & 15, q = l >> 4;
  __shared__ __attribute__((aligned(16))) short ys[16][136];
  const short* OP = (const short*)(ws + WS_OP);
  const float* LP = (const float*)(ws + WS_LP);
  const short* WZ = (const short*)(ws + WS_WZ);
  const float* wzs = (const float*)(ws + WS_WZS);
  const float* wzt = (const float*)(ws + WS_WZT);
  const int n0 = nt * 16;
  {
    int row = t >> 4, d8 = (t & 15) * 8;
    int n = n0 + row;
    float acc8[8] = {};
    float lsf = 0.f;
    #pragma unroll
    for (int mc = 0; mc < 4; ++mc) {
      int cb = mc * 4 + b;
      const short* p = OP + ((size_t)cb << 19) + ((size_t)n << 7) + d8;
      uint4 v = *(const uint4*)p;
      uint32_t uu[4] = {v.x, v.y, v.z, v.w};
      #pragma unroll
      for (int w = 0; w < 4; ++w) {
        union { uint32_t u; float f; } lo, hi;
        lo.u = uu[w] << 16; hi.u = uu[w] & 0xffff0000u;
        acc8[w * 2 + 0] += lo.f;
        acc8[w * 2 + 1] += hi.f;
      }
      lsf += LP[(cb << 12) + n];
    }
    float inv = 1.0f / lsf;
    short out8[8];
    #pragma unroll
    for (int j = 0; j < 8; ++j) out8[j] = f2bf(acc8[j] * inv);
    *(uint4*)&ys[row][d8] = *(uint4*)out8;
  }
  __syncthreads();
  bf16x8 a[4];
  #pragma unroll
  for (int kt = 0; kt < 4; ++kt) a[kt] = *(const bf16x8*)&ys[lr][kt * 32 + q * 8];
  f32x4 acc[4] = {};
  #pragma unroll
  for (int kt = 0; kt < 4; ++kt) {
    #pragma unroll
    for (int s = 0; s < 4; ++s) {
      const short* wp = WZ + (size_t)(wv * 64 + s * 16 + lr) * 128 + kt * 32 + q * 8;
      bf16x8 bf = *(const bf16x8*)wp;
      acc[s] = mfma16(a[kt], bf, acc[s]);
    }
  }
  #pragma unroll
  for (int s = 0; s < 4; ++s) {
    int c = wv * 64 + s * 16 + lr;
    float sc = wzs[c], sh = wzt[c];
    int nbase = n0 + q * 4;
    size_t base = ((size_t)(b * 256 + c) << 12) + nbase;
    float4 xv = *(const float4*)(x + base);
    float4 ov;
    ov.x = acc[s][0] * sc + sh + xv.x;
    ov.y = acc[s][1] * sc + sh + xv.y;
    ov.z = acc[s][2] * sc + sh + xv.z;
    ov.w = acc[s][3] * sc + sh + xv.w;
    *(float4*)(out + base) = ov;
  }
}

// ---------------- launcher ----------------
extern "C" void kernel_launch(void* const* d_in, const int* in_sizes, int n_in,
                              void* d_out, int out_size, void* d_ws, size_t ws_size,
                              hipStream_t stream) {
  const float* x       = (const float*)d_in[0];
  const float* theta_w = (const float*)d_in[1];
  const float* theta_b = (const float*)d_in[2];
  const float* tg      = (const float*)d_in[3];
  const float* tb      = (const float*)d_in[4];
  const float* tm      = (const float*)d_in[5];
  const float* tv      = (const float*)d_in[6];
  const float* phi_w   = (const float*)d_in[7];
  const float* phi_b   = (const float*)d_in[8];
  const float* pg      = (const float*)d_in[9];
  const float* pb      = (const float*)d_in[10];
  const float* pm      = (const float*)d_in[11];
  const float* pv      = (const float*)d_in[12];
  const float* g_w     = (const float*)d_in[13];
  const float* g_b     = (const float*)d_in[14];
  const float* wz_w    = (const float*)d_in[15];
  const float* wz_b    = (const float*)d_in[16];
  const float* bg      = (const float*)d_in[17];
  const float* bb      = (const float*)d_in[18];
  const float* bm      = (const float*)d_in[19];
  const float* bv      = (const float*)d_in[20];
  char* ws = (char*)d_ws;
  float* out = (float*)d_out;

  prep_kernel<<<384, 256, 0, stream>>>(theta_w, phi_w, g_w, wz_w,
                                       theta_b, tg, tb, tm, tv,
                                       phi_b, pg, pb, pm, pv,
                                       g_b, wz_b, bg, bb, bm, bv, ws);
  qkv_kernel<<<dim3(256, 4), 256, 0, stream>>>(x, ws);
  attn_kernel<<<1024, 256, 0, stream>>>(ws);
  proj_kernel<<<dim3(256, 4), 256, 0, stream>>>(x, ws, out);
}

// Round 8
// 197.367 us; speedup vs baseline: 1.1238x; 1.1238x over previous
//
#include <hip/hip_runtime.h>
#include <stdint.h>

typedef __attribute__((ext_vector_type(8))) short bf16x8;
typedef __attribute__((ext_vector_type(4))) float f32x4;
typedef __attribute__((ext_vector_type(16))) float f32x16;
typedef __attribute__((ext_vector_type(2))) unsigned int uint2v;

// ---------------- workspace layout (bytes) ----------------
#define WS_WQKV   0u               // 384*256 bf16 = 196608
#define WS_WZ     196608u          // 256*128 bf16 = 65536
#define WS_SCL    262144u          // 384 f32 (QKV fused BN scale)
#define WS_SHF    263680u          // 384 f32 (QKV fused BN shift)
#define WS_WZS    265216u          // 256 f32 (out BN scale)
#define WS_WZT    266240u          // 256 f32 (out BN shift)
#define WS_Q      524288u          // [4][4096][128] bf16 row-major (pre-scaled by s2)
#define WS_K      (WS_Q  + 4194304u)   // [4][64 tile][16 grp][64 lane][8] bf16 frag-tiled (32x32)
#define WS_VT     (WS_K  + 4194304u)   // [4][64 tile][16 grp][64 lane][8] bf16 frag-tiled (32x32)
#define WS_Y      (WS_VT + 4194304u)   // (spare)
#define WS_OP     (WS_Y  + 4194304u)   // [4 mc][4 b][4096][128] bf16 partials = 16 MB
#define WS_LP     (WS_OP + 16777216u)  // [4 mc][4 b][4096] f32 partial denoms = 256 KB

__device__ __forceinline__ short f2bf(float f) {
  union { float f; uint32_t u; } v; v.f = f;
  uint32_t r = v.u + 0x7fffu + ((v.u >> 16) & 1u);
  return (short)(r >> 16);
}

// round-half-up pair pack: 2 floats -> 2 bf16 in one u32 (cheap, <=1ulp bias)
__device__ __forceinline__ uint32_t pack2_bf16(float a, float b) {
  union { float f; uint32_t u; } x, y; x.f = a; y.f = b;
  return ((y.u + 0x8000u) & 0xffff0000u) | ((x.u + 0x8000u) >> 16);
}

// single-instruction pack: v_cvt_pk_bf16_f32 (RNE); no builtin on gfx950 (T12)
__device__ __forceinline__ uint32_t cvtpk_bf16(float a, float b) {
  uint32_t r;
  asm("v_cvt_pk_bf16_f32 %0, %1, %2" : "=v"(r) : "v"(a), "v"(b));
  return r;
}

__device__ __forceinline__ f32x4 mfma16(bf16x8 a, bf16x8 b, f32x4 c) {
  return __builtin_amdgcn_mfma_f32_16x16x32_bf16(a, b, c, 0, 0, 0);
}
__device__ __forceinline__ f32x16 mfma32(bf16x8 a, bf16x8 b, f32x16 c) {
  return __builtin_amdgcn_mfma_f32_32x32x16_bf16(a, b, c, 0, 0, 0);
}

// async global->LDS DMA, 16B/lane: dest = wave-uniform base + lane*16
__device__ __forceinline__ void load_lds16(const short* gp, short* lp) {
  __builtin_amdgcn_global_load_lds(
      (const __attribute__((address_space(1))) uint32_t*)gp,
      (__attribute__((address_space(3))) uint32_t*)lp, 16, 0, 0);
}

// ---------------- kernel 0: weight prep + BN folding ----------------
__global__ __launch_bounds__(256) void prep_kernel(
    const float* theta_w, const float* phi_w, const float* g_w, const float* wz_w,
    const float* theta_b, const float* tg, const float* tb, const float* tm, const float* tv,
    const float* phi_b,   const float* pg, const float* pb, const float* pm, const float* pv,
    const float* g_b,
    const float* wz_b, const float* bg, const float* bb, const float* bm, const float* bv,
    char* ws) {
  int idx = blockIdx.x * 256 + threadIdx.x;
  short* wqkv = (short*)(ws + WS_WQKV);
  if (idx < 98304) {
    float w;
    if (idx < 32768) w = theta_w[idx];
    else if (idx < 65536) w = phi_w[idx - 32768];
    else w = g_w[idx - 65536];
    wqkv[idx] = f2bf(w);
  }
  if (idx < 32768) ((short*)(ws + WS_WZ))[idx] = f2bf(wz_w[idx]);
  if (idx < 384) {
    float s, t;
    if (idx < 128)      { s = tg[idx] * rsqrtf(tv[idx] + 1e-5f);
                          t = (theta_b[idx] - tm[idx]) * s + tb[idx]; }
    else if (idx < 256) { int d = idx - 128; s = pg[d] * rsqrtf(pv[d] + 1e-5f);
                          t = (phi_b[d] - pm[d]) * s + pb[d]; }
    else                { int d = idx - 256; s = 1.0f; t = g_b[d]; }
    ((float*)(ws + WS_SCL))[idx] = s;
    ((float*)(ws + WS_SHF))[idx] = t;
  }
  if (idx < 256) {
    float s = bg[idx] * rsqrtf(bv[idx] + 1e-5f);
    float t = (wz_b[idx] - bm[idx]) * s + bb[idx];
    ((float*)(ws + WS_WZS))[idx] = s;
    ((float*)(ws + WS_WZT))[idx] = t;
  }
}

// ---------------- kernel 1: fused Q/K/V projection (+BN fold) ----------------
// (unchanged from R14) Per-s operand swap: Q/K computed as mfma16(w,x) so each
// thread owns 4 consecutive d -> all stores are 8B short4. K/V written in the
// 32x32-MFMA fragment-tiled order consumed by attn:
//   K: tile=n>>6; grp=mb*8+ks (mb=(n&63)>>5, ks=c>>4); slot=h*32+(n&31),
//      h=(c>>3)&1; elem=c&7.
//   V: grp=dt*4+ks2 (dt=d>>5, ks2=(n&63)>>4); slot=hv*32+(d&31),
//      hv=((n&63)>>3)&1; elem=n&7.
__global__ __launch_bounds__(256) void qkv_kernel(const float* __restrict__ x, char* ws) {
  const int nt2 = blockIdx.x, b = blockIdx.y;
  const int t = threadIdx.x;
  __shared__ __attribute__((aligned(16))) short xs[16][264];
  const short* wqkv = (const short*)(ws + WS_WQKV);
  const float* scl = (const float*)(ws + WS_SCL);
  const float* shf = (const float*)(ws + WS_SHF);
  const int n0 = nt2 * 16;
  #pragma unroll
  for (int i = 0; i < 4; ++i) {
    int chunk = i * 256 + t;
    int c = chunk >> 2, n4 = chunk & 3;
    const float4 v = *(const float4*)(x + ((size_t)(b * 256 + c) << 12) + n0 + n4 * 4);
    xs[n4 * 4 + 0][c] = f2bf(v.x);
    xs[n4 * 4 + 1][c] = f2bf(v.y);
    xs[n4 * 4 + 2][c] = f2bf(v.z);
    xs[n4 * 4 + 3][c] = f2bf(v.w);
  }
  __syncthreads();
  const int wv = t >> 6, l = t & 63, lr = l & 15, q = l >> 4;
  bf16x8 a[8];
  #pragma unroll
  for (int kt = 0; kt < 8; ++kt) a[kt] = *(const bf16x8*)&xs[lr][kt * 32 + q * 8];
  f32x4 acc[6] = {};
  #pragma unroll
  for (int kt = 0; kt < 8; ++kt) {
    #pragma unroll
    for (int s = 0; s < 6; ++s) {
      const short* wp = wqkv + (size_t)(wv * 96 + s * 16 + lr) * 256 + kt * 32 + q * 8;
      bf16x8 bf = *(const bf16x8*)wp;
      // wave-uniform branch: Q/K swapped orientation, V original
      if (wv * 96 + s * 16 < 256) acc[s] = mfma16(bf, a[kt], acc[s]);
      else                        acc[s] = mfma16(a[kt], bf, acc[s]);
    }
  }
  const float s2 = 0.08838834764831845f * 1.4426950408889634f;
  short* Qp = (short*)(ws + WS_Q)  + ((size_t)b << 19);
  short* Kt = (short*)(ws + WS_K)  + ((size_t)b << 19);
  short* Vt = (short*)(ws + WS_VT) + ((size_t)b << 19);
  #pragma unroll
  for (int s = 0; s < 6; ++s) {
    int dgb = wv * 96 + s * 16;
    if (dgb < 256) {
      // swapped: thread owns d = dgb+q*4+r (4 consecutive), n = n0+lr
      const int n = n0 + lr;
      const int d4 = dgb + q * 4;
      short4 pk;
      {
        short vals[4];
        #pragma unroll
        for (int r = 0; r < 4; ++r) {
          int dg = d4 + r;
          float sc = scl[dg], sh = shf[dg];
          if (dgb < 128) { sc *= s2; sh *= s2; }   // fold softmax scale into Q
          vals[r] = f2bf(acc[s][r] * sc + sh);
        }
        pk.x = vals[0]; pk.y = vals[1]; pk.z = vals[2]; pk.w = vals[3];
      }
      if (dgb < 128) {
        *(short4*)(Qp + (size_t)n * 128 + d4) = pk;
      } else {
        int c4 = d4 - 128;
        int tile = n >> 6, nn = n & 63;
        int mb = nn >> 5, rr = nn & 31;
        int ks = c4 >> 4, h = (c4 >> 3) & 1, e0 = c4 & 7;   // e0 in {0,4}
        size_t base = (size_t)tile * 8192 + (size_t)(mb * 8 + ks) * 512
                    + (size_t)(h * 32 + rr) * 8 + e0;
        *(short4*)(Kt + base) = pk;
      }
    } else {
      // original orientation: V (thread owns 4 consecutive n at fixed d)
      int dg = dgb + lr;
      float sc = scl[dg], sh = shf[dg];
      short4 pk;
      pk.x = f2bf(acc[s][0] * sc + sh);
      pk.y = f2bf(acc[s][1] * sc + sh);
      pk.z = f2bf(acc[s][2] * sc + sh);
      pk.w = f2bf(acc[s][3] * sc + sh);
      int d = dg - 256;
      int nbase = n0 + q * 4;
      int tile = nbase >> 6, nn = nbase & 63;
      int dt = d >> 5, rv = d & 31;
      int ks2 = nn >> 4, hv = (nn >> 3) & 1, e0 = nn & 7;   // e0 in {0,4}
      size_t base = (size_t)tile * 8192 + (size_t)(dt * 4 + ks2) * 512
                  + (size_t)(hv * 32 + rv) * 8 + e0;
      *(short4*)(Vt + base) = pk;
    }
  }
}

// ---------------- kernel 2: flash attention, R13 body + VALU-shrunk softmax ---
// R18: R7's d-split failure proved attn is VALU/LDS-issue-throughput bound
// (occupancy 29%, VALUBusy 54%, time +47% from duplicated softmax). So: back
// to the proven R13 structure (53.4us) and cut softmax VALU instructions on
// the critical path: (a) pack2_bf16 (5 VALU ops) -> v_cvt_pk_bf16_f32 (1 op,
// RNE, register-only inline asm -- T12); (b) 32-deep serial lsum dependency
// chain -> pairwise tree (depth 5; hipcc won't reassociate FP without
// fast-math). Net ~ -80 VALU instr per tile per wave on a VALU-bound kernel.
__global__ __launch_bounds__(256, 2) void attn_kernel(char* ws) {
  const int g = blockIdx.x;
  const int b = (g & 7) >> 1;
  const int idx = ((g >> 3) << 1) | (g & 1);     // 0..127
  const int nt = idx >> 2, mc = idx & 3;         // nt 0..31, mc 0..3
  const int t = threadIdx.x, w = t >> 6, l = t & 63;
  const int lq = l & 31, h = l >> 5;
  __shared__ __attribute__((aligned(16))) short ks0[16][512];   // grp mb*8+ks
  __shared__ __attribute__((aligned(16))) short vs0[16][512];   // grp dt*4+ks2
  __shared__ __attribute__((aligned(16))) short ks1[16][512];
  __shared__ __attribute__((aligned(16))) short vs1[16][512];
  const short* Q  = (const short*)(ws + WS_Q)  + ((size_t)b << 19);
  const short* Kt = (const short*)(ws + WS_K)  + ((size_t)b << 19);
  const short* Vt = (const short*)(ws + WS_VT) + ((size_t)b << 19);
  const int n0w = nt * 128 + w * 32;
  // Q fragments resident as B-operands (pre-scaled by s2 in qkv):
  // col = lq = Q-row, k = ks*16 + h*8 + e
  bf16x8 qf[8];
  #pragma unroll
  for (int ks = 0; ks < 8; ++ks)
    qf[ks] = *(const bf16x8*)(Q + (size_t)(n0w + lq) * 128 + ks * 16 + h * 8);
  f32x16 o[4] = {};    // o[dt]: O^T[32dt + row(reg,h)][q=lq]
  float lsum = 0.f;

  const short* kbase = Kt + (size_t)(mc * 16) * 8192;
  const short* vbase = Vt + (size_t)(mc * 16) * 8192;

  auto stage = [&](short (*KS)[512], short (*VS)[512], int it) {
    const short* kg = kbase + (size_t)it * 8192;
    const short* vg = vbase + (size_t)it * 8192;
    #pragma unroll
    for (int i = 0; i < 4; ++i) {
      int gi = i * 4 + w;
      load_lds16(kg + gi * 512 + l * 8, &KS[gi][0]);
      load_lds16(vg + gi * 512 + l * 8, &VS[gi][0]);
    }
  };

  auto compute = [&](short (*ksl)[512], short (*vsl)[512]) {
    // S^T = K * Q^T : A = K-frag (row = kv, k = c), B = qf
    f32x16 sacc[2] = {};
    __builtin_amdgcn_s_setprio(1);
    #pragma unroll
    for (int ks = 0; ks < 8; ++ks) {
      #pragma unroll
      for (int mb = 0; mb < 2; ++mb) {
        bf16x8 kf = *(const bf16x8*)&ksl[mb * 8 + ks][l * 8];
        sacc[mb] = mfma32(kf, qf[ks], sacc[mb]);
      }
    }
    __builtin_amdgcn_s_setprio(0);
    // softmax + in-register P fragment build (T12): no LDS, minimal VALU.
    bf16x8 pf[4];   // pf[2*mb+k] covers kv rows 32mb+16k .. +15
    #pragma unroll
    for (int mb = 0; mb < 2; ++mb) {
      float e[16];
      #pragma unroll
      for (int r = 0; r < 16; ++r) e[r] = exp2f(sacc[mb][r]);
      // pairwise tree sum (depth ~5, vs 16-deep serial chain)
      float t0 = (e[0] + e[1]) + (e[2] + e[3]);
      float t1 = (e[4] + e[5]) + (e[6] + e[7]);
      float t2 = (e[8] + e[9]) + (e[10] + e[11]);
      float t3 = (e[12] + e[13]) + (e[14] + e[15]);
      lsum += (t0 + t1) + (t2 + t3);
      #pragma unroll
      for (int k = 0; k < 2; ++k) {
        uint32_t va0 = cvtpk_bf16(e[8 * k + 0], e[8 * k + 1]);
        uint32_t va1 = cvtpk_bf16(e[8 * k + 2], e[8 * k + 3]);
        uint32_t vb0 = cvtpk_bf16(e[8 * k + 4], e[8 * k + 5]);
        uint32_t vb1 = cvtpk_bf16(e[8 * k + 6], e[8 * k + 7]);
        uint2v s0 = __builtin_amdgcn_permlane32_swap(va0, vb0, false, false);
        uint2v s1 = __builtin_amdgcn_permlane32_swap(va1, vb1, false, false);
        union { uint32_t u[4]; bf16x8 v; } pk;
        pk.u[0] = s0[0]; pk.u[1] = s1[0]; pk.u[2] = s0[1]; pk.u[3] = s1[1];
        pf[2 * mb + k] = pk.v;
      }
    }
    // O^T += V^T * P^T : A = V-frag (row = d, k = kv), B = pf
    __builtin_amdgcn_s_setprio(1);
    #pragma unroll
    for (int dt = 0; dt < 4; ++dt) {
      #pragma unroll
      for (int ks2 = 0; ks2 < 4; ++ks2) {
        bf16x8 vf = *(const bf16x8*)&vsl[dt * 4 + ks2][l * 8];
        o[dt] = mfma32(vf, pf[ks2], o[dt]);
      }
    }
    __builtin_amdgcn_s_setprio(0);
  };

  // depth-1 prefetch pipeline: single barrier per tile.
  stage(ks0, vs0, 0);
  __syncthreads();
  for (int it2 = 0; it2 < 8; ++it2) {
    stage(ks1, vs1, it2 * 2 + 1);
    compute(ks0, vs0);
    __syncthreads();
    if (it2 < 7) stage(ks0, vs0, it2 * 2 + 2);
    compute(ks1, vs1);
    __syncthreads();
  }

  // epilogue: write unnormalized partials
  const int cb = mc * 4 + b;
  float* LP = (float*)(ws + WS_LP) + ((size_t)cb << 12);
  {
    float s = lsum;
    s += __shfl_xor(s, 32, 64);
    if (l < 32) LP[n0w + l] = s;
  }
  short* OPc = (short*)(ws + WS_OP) + ((size_t)cb << 19);
  #pragma unroll
  for (int dt = 0; dt < 4; ++dt) {
    #pragma unroll
    for (int rg = 0; rg < 4; ++rg) {
      short4 pk;
      pk.x = f2bf(o[dt][rg * 4 + 0]);
      pk.y = f2bf(o[dt][rg * 4 + 1]);
      pk.z = f2bf(o[dt][rg * 4 + 2]);
      pk.w = f2bf(o[dt][rg * 4 + 3]);
      *(short4*)&OPc[((size_t)(n0w + lq) << 7) + dt * 32 + rg * 8 + h * 4] = pk;
    }
  }
}

// ---------------- kernel 3: merge partials + W_z projection + BN2d + residual ----
// grid (256 nt of 16 rows, 4 b); block 256 = 4 waves (wave = c-quarter).
__global__ __launch_bounds__(256) void proj_kernel(const float* __restrict__ x,
                                                   char* ws, float* __restrict__ out) {
  const int nt = blockIdx.x, b = blockIdx.y;
  const int t = threadIdx.x, wv = t >> 6, l = t & 63, lr = l & 15, q = l >> 4;
  __shared__ __attribute__((aligned(16))) short ys[16][136];
  const short* OP = (const short*)(ws + WS_OP);
  const float* LP = (const float*)(ws + WS_LP);
  const short* WZ = (const short*)(ws + WS_WZ);
  const float* wzs = (const float*)(ws + WS_WZS);
  const float* wzt = (const float*)(ws + WS_WZT);
  const int n0 = nt * 16;
  {
    int row = t >> 4, d8 = (t & 15) * 8;
    int n = n0 + row;
    float acc8[8] = {};
    float lsf = 0.f;
    #pragma unroll
    for (int mc = 0; mc < 4; ++mc) {
      int cb = mc * 4 + b;
      const short* p = OP + ((size_t)cb << 19) + ((size_t)n << 7) + d8;
      uint4 v = *(const uint4*)p;
      uint32_t uu[4] = {v.x, v.y, v.z, v.w};
      #pragma unroll
      for (int w = 0; w < 4; ++w) {
        union { uint32_t u; float f; } lo, hi;
        lo.u = uu[w] << 16; hi.u = uu[w] & 0xffff0000u;
        acc8[w * 2 + 0] += lo.f;
        acc8[w * 2 + 1] += hi.f;
      }
      lsf += LP[(cb << 12) + n];
    }
    float inv = 1.0f / lsf;
    short out8[8];
    #pragma unroll
    for (int j = 0; j < 8; ++j) out8[j] = f2bf(acc8[j] * inv);
    *(uint4*)&ys[row][d8] = *(uint4*)out8;
  }
  __syncthreads();
  bf16x8 a[4];
  #pragma unroll
  for (int kt = 0; kt < 4; ++kt) a[kt] = *(const bf16x8*)&ys[lr][kt * 32 + q * 8];
  f32x4 acc[4] = {};
  #pragma unroll
  for (int kt = 0; kt < 4; ++kt) {
    #pragma unroll
    for (int s = 0; s < 4; ++s) {
      const short* wp = WZ + (size_t)(wv * 64 + s * 16 + lr) * 128 + kt * 32 + q * 8;
      bf16x8 bf = *(const bf16x8*)wp;
      acc[s] = mfma16(a[kt], bf, acc[s]);
    }
  }
  #pragma unroll
  for (int s = 0; s < 4; ++s) {
    int c = wv * 64 + s * 16 + lr;
    float sc = wzs[c], sh = wzt[c];
    int nbase = n0 + q * 4;
    size_t base = ((size_t)(b * 256 + c) << 12) + nbase;
    float4 xv = *(const float4*)(x + base);
    float4 ov;
    ov.x = acc[s][0] * sc + sh + xv.x;
    ov.y = acc[s][1] * sc + sh + xv.y;
    ov.z = acc[s][2] * sc + sh + xv.z;
    ov.w = acc[s][3] * sc + sh + xv.w;
    *(float4*)(out + base) = ov;
  }
}

// ---------------- launcher ----------------
extern "C" void kernel_launch(void* const* d_in, const int* in_sizes, int n_in,
                              void* d_out, int out_size, void* d_ws, size_t ws_size,
                              hipStream_t stream) {
  const float* x       = (const float*)d_in[0];
  const float* theta_w = (const float*)d_in[1];
  const float* theta_b = (const float*)d_in[2];
  const float* tg      = (const float*)d_in[3];
  const float* tb      = (const float*)d_in[4];
  const float* tm      = (const float*)d_in[5];
  const float* tv      = (const float*)d_in[6];
  const float* phi_w   = (const float*)d_in[7];
  const float* phi_b   = (const float*)d_in[8];
  const float* pg      = (const float*)d_in[9];
  const float* pb      = (const float*)d_in[10];
  const float* pm      = (const float*)d_in[11];
  const float* pv      = (const float*)d_in[12];
  const float* g_w     = (const float*)d_in[13];
  const float* g_b     = (const float*)d_in[14];
  const float* wz_w    = (const float*)d_in[15];
  const float* wz_b    = (const float*)d_in[16];
  const float* bg      = (const float*)d_in[17];
  const float* bb      = (const float*)d_in[18];
  const float* bm      = (const float*)d_in[19];
  const float* bv      = (const float*)d_in[20];
  char* ws = (char*)d_ws;
  float* out = (float*)d_out;

  prep_kernel<<<384, 256, 0, stream>>>(theta_w, phi_w, g_w, wz_w,
                                       theta_b, tg, tb, tm, tv,
                                       phi_b, pg, pb, pm, pv,
                                       g_b, wz_b, bg, bb, bm, bv, ws);
  qkv_kernel<<<dim3(256, 4), 256, 0, stream>>>(x, ws);
  attn_kernel<<<512, 256, 0, stream>>>(ws);
  proj_kernel<<<dim3(256, 4), 256, 0, stream>>>(x, ws, out);
}